// Round 1
// baseline (641.148 us; speedup 1.0000x reference)
//
#include <hip/hip_runtime.h>

#define NUM_JOINTS 24

// Extract component c (compile-time constant after unroll) from a float4.
__device__ __forceinline__ float f4c(const float4& v, int c) {
    switch (c & 3) {
        case 0: return v.x;
        case 1: return v.y;
        case 2: return v.z;
        default: return v.w;
    }
}

__global__ __launch_bounds__(256) void fk_kernel(
    const float* __restrict__ local_rots,  // [B, 24, 3, 3]
    const float* __restrict__ root_pos,    // [B, 3]
    const float* __restrict__ offsets,     // [24, 3]
    float* __restrict__ out_pos,           // [B, 24, 3]
    float* __restrict__ out_rot,           // [B, 24, 3, 3]
    int B)
{
    const int b = blockIdx.x * blockDim.x + threadIdx.x;
    if (b >= B) return;

    constexpr int par[NUM_JOINTS] =
        {-1,0,0,0,1,2,3,4,5,6,7,8,9,9,9,12,13,14,16,17,18,19,20,21};

    const float4* __restrict__ lr4 =
        reinterpret_cast<const float4*>(local_rots) + (size_t)b * 54;
    float4* __restrict__ or4 = reinterpret_cast<float4*>(out_rot) + (size_t)b * 54;
    float4* __restrict__ op4 = reinterpret_cast<float4*>(out_pos) + (size_t)b * 18;

    // Full FK state; fully unrolled constant indexing -> SROA to registers,
    // liveness keeps at most ~3 rotations alive at any point.
    float R[NUM_JOINTS][9];
    float P[NUM_JOINTS][3];

    P[0][0] = root_pos[(size_t)b * 3 + 0];
    P[0][1] = root_pos[(size_t)b * 3 + 1];
    P[0][2] = root_pos[(size_t)b * 3 + 2];

    #pragma unroll
    for (int g = 0; g < 6; ++g) {
        // Load 4 joints' local rotations = 36 floats = 9 aligned float4s.
        float4 L[9];
        #pragma unroll
        for (int q = 0; q < 9; ++q) L[q] = lr4[g * 9 + q];

        #pragma unroll
        for (int t = 0; t < 4; ++t) {
            const int j = g * 4 + t;
            // local element (m,k) of joint j sits at group dword d = 9t+3m+k
            float Ll[9];
            #pragma unroll
            for (int e = 0; e < 9; ++e) {
                const int d = 9 * t + e;
                Ll[e] = f4c(L[d >> 2], d & 3);
            }
            if (j == 0) {
                #pragma unroll
                for (int e = 0; e < 9; ++e) R[0][e] = Ll[e];
            } else {
                const int p = par[j];
                #pragma unroll
                for (int i = 0; i < 3; ++i) {
                    #pragma unroll
                    for (int k = 0; k < 3; ++k) {
                        R[j][i * 3 + k] = R[p][i * 3 + 0] * Ll[0 * 3 + k]
                                        + R[p][i * 3 + 1] * Ll[1 * 3 + k]
                                        + R[p][i * 3 + 2] * Ll[2 * 3 + k];
                    }
                }
                // offsets[j] is wave-uniform (j constant) -> scalar loads
                const float o0 = offsets[j * 3 + 0];
                const float o1 = offsets[j * 3 + 1];
                const float o2 = offsets[j * 3 + 2];
                #pragma unroll
                for (int i = 0; i < 3; ++i) {
                    P[j][i] = P[p][i] + R[p][i * 3 + 0] * o0
                                      + R[p][i * 3 + 1] * o1
                                      + R[p][i * 3 + 2] * o2;
                }
            }
        }

        // Store this group's 4 global rots: 36 floats -> 9 float4
        #pragma unroll
        for (int q = 0; q < 9; ++q) {
            float4 v;
            v.x = R[g * 4 + (4 * q + 0) / 9][(4 * q + 0) % 9];
            v.y = R[g * 4 + (4 * q + 1) / 9][(4 * q + 1) % 9];
            v.z = R[g * 4 + (4 * q + 2) / 9][(4 * q + 2) % 9];
            v.w = R[g * 4 + (4 * q + 3) / 9][(4 * q + 3) % 9];
            or4[g * 9 + q] = v;
        }
        // Store this group's 4 global positions: 12 floats -> 3 float4
        #pragma unroll
        for (int q = 0; q < 3; ++q) {
            float4 v;
            v.x = P[g * 4 + (4 * q + 0) / 3][(4 * q + 0) % 3];
            v.y = P[g * 4 + (4 * q + 1) / 3][(4 * q + 1) % 3];
            v.z = P[g * 4 + (4 * q + 2) / 3][(4 * q + 2) % 3];
            v.w = P[g * 4 + (4 * q + 3) / 3][(4 * q + 3) % 3];
            op4[g * 3 + q] = v;
        }
    }
}

extern "C" void kernel_launch(void* const* d_in, const int* in_sizes, int n_in,
                              void* d_out, int out_size, void* d_ws, size_t ws_size,
                              hipStream_t stream) {
    const float* local_rots = (const float*)d_in[0];
    const float* root_pos   = (const float*)d_in[1];
    const float* offsets    = (const float*)d_in[2];

    const int B = in_sizes[1] / 3;  // root_pos is [B,3]

    float* out      = (float*)d_out;
    float* out_pos  = out;                       // [B,24,3]
    float* out_rot  = out + (size_t)B * 24 * 3;  // [B,24,3,3]

    const int block = 256;
    const int grid  = (B + block - 1) / block;
    fk_kernel<<<grid, block, 0, stream>>>(local_rots, root_pos, offsets,
                                          out_pos, out_rot, B);
}

// Round 2
// 457.346 us; speedup vs baseline: 1.4019x; 1.4019x over previous
//
#include <hip/hip_runtime.h>

#define NJ 24

// ---- compile-time float4 component access (indices constant after unroll) ----
__device__ __forceinline__ float f4c(const float4& v, int c) {
    switch (c & 3) {
        case 0: return v.x;
        case 1: return v.y;
        case 2: return v.z;
        default: return v.w;
    }
}
__device__ __forceinline__ void f4s(float4& v, int c, float x) {
    switch (c & 3) {
        case 0: v.x = x; break;
        case 1: v.y = x; break;
        case 2: v.z = x; break;
        default: v.w = x; break;
    }
}

// One wave (64 threads) per block; each thread = one batch element.
// LDS staging makes ALL global traffic fully-coalesced 1KB-per-instruction:
//   phase 1: coop-load 64 elements' local rots (54 float4 each) -> LDS rows
//   phase 2: per-thread FK from own LDS row; R[j] overwrites L[j] in place;
//            positions staged to a second small LDS buffer
//   phase 3: coop-store rot (55KB) + pos (18KB) contiguous regions
// Row stride padded to 55 / 19 float4 (= 4*odd dwords): lane-stride 28 dwords
// mod 32 covers all bank quads -> no extra LDS bank conflicts on b128 ops.
__global__ __launch_bounds__(64) void fk_kernel(
    const float* __restrict__ local_rots,  // [B, 24, 3, 3]
    const float* __restrict__ root_pos,    // [B, 3]
    const float* __restrict__ offsets,     // [24, 3]
    float* __restrict__ out_pos,           // [B, 24, 3]
    float* __restrict__ out_rot,           // [B, 24, 3, 3]
    int B)
{
    constexpr int ROT_F4 = 54;   // float4 per element (rot in == rot out)
    constexpr int ROT_ST = 55;   // padded LDS row stride (float4)
    constexpr int POS_F4 = 18;   // float4 per element (pos out)
    constexpr int POS_ST = 19;

    __shared__ float4 s_rot[64 * ROT_ST];  // 56320 B
    __shared__ float4 s_pos[64 * POS_ST];  // 19456 B

    const int l = threadIdx.x;                       // lane 0..63
    const size_t blk = (size_t)blockIdx.x * 64;      // first element of block

    const float4* __restrict__ in4 =
        reinterpret_cast<const float4*>(local_rots) + blk * ROT_F4;

    // root position: 3 scalar loads per thread (3 MB total, L1/L3-friendly)
    float p0x = root_pos[(blk + l) * 3 + 0];
    float p0y = root_pos[(blk + l) * 3 + 1];
    float p0z = root_pos[(blk + l) * 3 + 2];

    // ---- phase 1: cooperative coalesced load of all 64 elements' rots ----
    #pragma unroll
    for (int i = 0; i < ROT_F4; ++i) {
        const int f = i * 64 + l;          // 0..3455
        const int e = f / ROT_F4;          // owner element (const-divide)
        const int q = f % ROT_F4;          // float4 index within element
        s_rot[e * ROT_ST + q] = in4[f];
    }
    __syncthreads();

    // ---- phase 2: per-thread FK over own row ----
    constexpr int par[NJ] =
        {-1,0,0,0,1,2,3,4,5,6,7,8,9,9,9,12,13,14,16,17,18,19,20,21};

    float R[NJ][9];
    float P[NJ][3];
    P[0][0] = p0x; P[0][1] = p0y; P[0][2] = p0z;

    #pragma unroll
    for (int g = 0; g < 6; ++g) {
        // read this group's 4 joints (9 float4 = 36 floats) from own row
        float4 Lf[9];
        #pragma unroll
        for (int k = 0; k < 9; ++k) Lf[k] = s_rot[l * ROT_ST + g * 9 + k];

        #pragma unroll
        for (int t = 0; t < 4; ++t) {
            const int j = g * 4 + t;
            float Ll[9];
            #pragma unroll
            for (int e = 0; e < 9; ++e) {
                const int d = 9 * t + e;
                Ll[e] = f4c(Lf[d >> 2], d & 3);
            }
            if (j == 0) {
                #pragma unroll
                for (int e = 0; e < 9; ++e) R[0][e] = Ll[e];
            } else {
                const int p = par[j];
                #pragma unroll
                for (int i = 0; i < 3; ++i) {
                    #pragma unroll
                    for (int k = 0; k < 3; ++k) {
                        R[j][i * 3 + k] = R[p][i * 3 + 0] * Ll[0 * 3 + k]
                                        + R[p][i * 3 + 1] * Ll[1 * 3 + k]
                                        + R[p][i * 3 + 2] * Ll[2 * 3 + k];
                    }
                }
                const float o0 = offsets[j * 3 + 0];   // wave-uniform -> scalar
                const float o1 = offsets[j * 3 + 1];
                const float o2 = offsets[j * 3 + 2];
                #pragma unroll
                for (int i = 0; i < 3; ++i) {
                    P[j][i] = P[p][i] + R[p][i * 3 + 0] * o0
                                      + R[p][i * 3 + 1] * o1
                                      + R[p][i * 3 + 2] * o2;
                }
            }
        }

        // write back global rots of this group in place (L consumed above)
        #pragma unroll
        for (int k = 0; k < 9; ++k) {
            float4 v;
            #pragma unroll
            for (int c = 0; c < 4; ++c) {
                const int d = 4 * k + c;               // 0..35 within group
                f4s(v, c, R[g * 4 + d / 9][d % 9]);
            }
            s_rot[l * ROT_ST + g * 9 + k] = v;
        }
        // stage this group's 4 positions (3 float4)
        #pragma unroll
        for (int k = 0; k < 3; ++k) {
            float4 v;
            #pragma unroll
            for (int c = 0; c < 4; ++c) {
                const int d = 4 * k + c;               // 0..11 within group
                f4s(v, c, P[g * 4 + d / 3][d % 3]);
            }
            s_pos[l * POS_ST + g * 3 + k] = v;
        }
    }
    __syncthreads();

    // ---- phase 3: cooperative coalesced stores ----
    float4* __restrict__ orot = reinterpret_cast<float4*>(out_rot) + blk * ROT_F4;
    #pragma unroll
    for (int i = 0; i < ROT_F4; ++i) {
        const int f = i * 64 + l;
        orot[f] = s_rot[(f / ROT_F4) * ROT_ST + (f % ROT_F4)];
    }
    float4* __restrict__ opos = reinterpret_cast<float4*>(out_pos) + blk * POS_F4;
    #pragma unroll
    for (int i = 0; i < POS_F4; ++i) {
        const int f = i * 64 + l;
        opos[f] = s_pos[(f / POS_F4) * POS_ST + (f % POS_F4)];
    }
}

extern "C" void kernel_launch(void* const* d_in, const int* in_sizes, int n_in,
                              void* d_out, int out_size, void* d_ws, size_t ws_size,
                              hipStream_t stream) {
    const float* local_rots = (const float*)d_in[0];
    const float* root_pos   = (const float*)d_in[1];
    const float* offsets    = (const float*)d_in[2];

    const int B = in_sizes[1] / 3;  // root_pos is [B,3]

    float* out      = (float*)d_out;
    float* out_pos  = out;                       // [B,24,3]
    float* out_rot  = out + (size_t)B * 24 * 3;  // [B,24,3,3]

    const int block = 64;                        // one wave per block
    const int grid  = B / block;                 // B = 262144 -> 4096
    fk_kernel<<<grid, block, 0, stream>>>(local_rots, root_pos, offsets,
                                          out_pos, out_rot, B);
}